// Round 4
// baseline (1044.977 us; speedup 1.0000x reference)
//
#include <hip/hip_runtime.h>

// AttentionBiasHead: B=32, L=512, DIM_IN=512, DQ=DK=128, DS=256, DMLP=128
// Round 4: inputs f32 (proven r1), mask auto-detected byte/int32 (r2==r3 =>
// byte), OUTPUT FLOAT32 (r2/r3 bit-identical absmax 109 => harness reads f32;
// reference output dtype is f32). Same pipeline as round 3, f32 out writes.

typedef unsigned int  u32;
typedef unsigned short u16;

__device__ __forceinline__ float waveMax(float v) {
#pragma unroll
    for (int o = 32; o > 0; o >>= 1) v = fmaxf(v, __shfl_xor(v, o, 64));
    return v;
}
__device__ __forceinline__ float waveSum(float v) {
#pragma unroll
    for (int o = 32; o > 0; o >>= 1) v += __shfl_xor(v, o, 64);
    return v;
}

// ---------------------------------------------------------------------------
// Mask dtype detector (scans 8.4 MB, safe under byte or int32 layout).
// ---------------------------------------------------------------------------
__global__ __launch_bounds__(256) void mask_detect(const u32* __restrict__ m,
                                                   u32* __restrict__ flag)
{
    const size_t t = (size_t)blockIdx.x * 256 + threadIdx.x;   // grid 2048
    u32 any = 0;
#pragma unroll
    for (int l = 0; l < 4; ++l) any |= (m[t * 4 + l] > 1u) ? 1u : 0u;
    if (__ballot(any)) {
        if ((threadIdx.x & 63) == 0) atomicOr(flag, 1u);
    }
}

__global__ __launch_bounds__(256) void mask_canon(const void* __restrict__ mask,
                                                  const u32* __restrict__ flag,
                                                  unsigned char* __restrict__ canon)
{
    const size_t i = (size_t)blockIdx.x * 256 + threadIdx.x;   // grid 32768
    if (*flag == 0) canon[i] = (((const int*)mask)[i] != 0) ? 1 : 0;
    else            canon[i] = (((const unsigned char*)mask)[i] != 0) ? 1 : 0;
}

// ---------------------------------------------------------------------------
// QKV projection: block = 8 rows of one stream. X rows in LDS, W coalesced.
// ---------------------------------------------------------------------------
__global__ __launch_bounds__(256) void proj_kernel(
    const float* __restrict__ Xq, const float* __restrict__ Xk, const float* __restrict__ Xv,
    const float* __restrict__ Wq, const float* __restrict__ Wk, const float* __restrict__ Wv,
    const float* __restrict__ Bq, const float* __restrict__ Bk, const float* __restrict__ Bv,
    float* __restrict__ Yq, float* __restrict__ Yk, float* __restrict__ Yv)
{
    const float* X; const float* W; const float* Bi; float* Y;
    if (blockIdx.y == 0)      { X = Xq; W = Wq; Bi = Bq; Y = Yq; }
    else if (blockIdx.y == 1) { X = Xk; W = Wk; Bi = Bk; Y = Yk; }
    else                      { X = Xv; W = Wv; Bi = Bv; Y = Yv; }

    __shared__ float xs[8 * 512];                 // 16 KiB
    const int tid = threadIdx.x;
    const int R0 = blockIdx.x * 8;                // grid.x = 2048

    const float4* Xf4 = (const float4*)(X + (size_t)R0 * 512);
#pragma unroll
    for (int l = 0; l < 4; ++l)
        *(float4*)&xs[(l * 256 + tid) * 4] = Xf4[l * 256 + tid];
    __syncthreads();

    const int n = tid & 127, rh = tid >> 7;
    float a0 = 0.f, a1 = 0.f, a2 = 0.f, a3 = 0.f;
    for (int d = 0; d < 512; ++d) {
        const float w = W[(size_t)d * 128 + n];
        a0 += xs[(rh * 4 + 0) * 512 + d] * w;
        a1 += xs[(rh * 4 + 1) * 512 + d] * w;
        a2 += xs[(rh * 4 + 2) * 512 + d] * w;
        a3 += xs[(rh * 4 + 3) * 512 + d] * w;
    }
    const float bn = Bi[n];
    Y[(size_t)(R0 + rh * 4 + 0) * 128 + n] = a0 + bn;
    Y[(size_t)(R0 + rh * 4 + 1) * 128 + n] = a1 + bn;
    Y[(size_t)(R0 + rh * 4 + 2) * 128 + n] = a2 + bn;
    Y[(size_t)(R0 + rh * 4 + 3) * 128 + n] = a3 + bn;
}

// ---------------------------------------------------------------------------
// h = relu(sf @ Wb1 + bb1)   [32,256]@[256,128] -> [32,128] f32
// ---------------------------------------------------------------------------
__global__ __launch_bounds__(256) void mlp1_kernel(
    const float* __restrict__ sf, const float* __restrict__ Wb1,
    const float* __restrict__ bb1, float* __restrict__ h)
{
    const int t = blockIdx.x * 256 + threadIdx.x;   // grid 16 -> 4096
    const int b = t >> 7, n = t & 127;
    float acc = bb1[n];
    for (int m = 0; m < 256; ++m)
        acc += sf[b * 256 + m] * Wb1[m * 128 + n];
    h[t] = fmaxf(acc, 0.0f);
}

// ---------------------------------------------------------------------------
// bias = h @ Wb2 + bb2 -> [32, 262144] f32. Wb2 (128 MB) streamed once.
// ---------------------------------------------------------------------------
__global__ __launch_bounds__(256) void bias_mlp2(
    const float* __restrict__ h, const float* __restrict__ Wb2,
    const float* __restrict__ bb2, float* __restrict__ biasf)
{
    __shared__ float hs[4096];
    const int tid = threadIdx.x;
#pragma unroll
    for (int l = 0; l < 16; ++l) hs[l * 256 + tid] = h[l * 256 + tid];
    __syncthreads();

    const size_t n = (size_t)blockIdx.x * 256 + tid;   // grid 1024
    float acc[32];
    const float bb = bb2[n];
#pragma unroll
    for (int b = 0; b < 32; ++b) acc[b] = bb;

    for (int m4 = 0; m4 < 32; ++m4) {
        const float w0 = Wb2[(size_t)(m4 * 4 + 0) * 262144 + n];
        const float w1 = Wb2[(size_t)(m4 * 4 + 1) * 262144 + n];
        const float w2 = Wb2[(size_t)(m4 * 4 + 2) * 262144 + n];
        const float w3 = Wb2[(size_t)(m4 * 4 + 3) * 262144 + n];
#pragma unroll
        for (int b = 0; b < 32; ++b) {
            const float4 hv = *(const float4*)&hs[b * 128 + m4 * 4];
            acc[b] += hv.x * w0 + hv.y * w1 + hv.z * w2 + hv.w * w3;
        }
    }
#pragma unroll
    for (int b = 0; b < 32; ++b)
        biasf[(size_t)b * 262144 + n] = acc[b];
}

// ---------------------------------------------------------------------------
// Attention: one block (256 thr) per (b,i) row. f32 in, f32 out.
// ---------------------------------------------------------------------------
__global__ __launch_bounds__(256) void attn_kernel(
    const float* __restrict__ qf, const float* __restrict__ kf, const float* __restrict__ vf,
    const unsigned char* __restrict__ canon, const float* __restrict__ biasf,
    float* __restrict__ out)
{
    const int row = blockIdx.x;           // b*512 + i, grid 16384
    const int b = row >> 9, i = row & 511;
    const int tid = threadIdx.x;

    __shared__ float qrow[128];
    __shared__ float attnS[512];
    __shared__ float red[8];
    __shared__ float partial[2][128];

    if (tid < 128) qrow[tid] = qf[(size_t)row * 128 + tid];
    __syncthreads();

    // scores for j = tid and j = tid + 256
    float s0 = 0.f, s1 = 0.f;
    {
        const float* k0 = kf + (size_t)(b * 512 + tid) * 128;
        const float* k1 = k0 + 256 * 128;
        for (int d = 0; d < 128; ++d) {
            const float q = qrow[d];
            s0 += q * k0[d];
            s1 += q * k1[d];
        }
        s0 *= 0.08838834764831845f;       // 1/sqrt(128)
        s1 *= 0.08838834764831845f;
        const unsigned char* mrow = canon + (size_t)row * 512;
        if (mrow[tid])       s0 = 1e-9f;
        if (mrow[tid + 256]) s1 = 1e-9f;
    }

    // softmax over 512
    const int wid = tid >> 6;
    float m = waveMax(fmaxf(s0, s1));
    if ((tid & 63) == 0) red[wid] = m;
    __syncthreads();
    const float mx = fmaxf(fmaxf(red[0], red[1]), fmaxf(red[2], red[3]));
    const float e0 = __expf(s0 - mx), e1 = __expf(s1 - mx);
    float ws = waveSum(e0 + e1);
    if ((tid & 63) == 0) red[4 + wid] = ws;
    __syncthreads();
    const float inv = 1.0f / (red[4] + red[5] + red[6] + red[7]);

    {
        const float* brow = biasf + (size_t)b * 262144 + (size_t)i * 512;
        attnS[tid]       = e0 * inv + brow[tid];
        attnS[tid + 256] = e1 * inv + brow[tid + 256];
    }
    __syncthreads();

    // out = attn @ v : two j-halves of 256
    {
        const int d = tid & 127, jh = tid >> 7;
        const float* vp = vf + (size_t)b * 512 * 128 + (size_t)jh * 256 * 128;
        float a = 0.f;
        for (int j = 0; j < 256; ++j)
            a += attnS[jh * 256 + j] * vp[(size_t)j * 128 + d];
        partial[jh][d] = a;
    }
    __syncthreads();

    if (tid < 128)
        out[(size_t)row * 128 + tid] = partial[0][tid] + partial[1][tid];
}

// ---------------------------------------------------------------------------
extern "C" void kernel_launch(void* const* d_in, const int* in_sizes, int n_in,
                              void* d_out, int out_size, void* d_ws, size_t ws_size,
                              hipStream_t stream)
{
    const float* query = (const float*)d_in[0];
    const float* key_  = (const float*)d_in[1];
    const float* value = (const float*)d_in[2];
    const float* sf    = (const float*)d_in[3];
    const void*  mask  = d_in[4];
    const float* Wq  = (const float*)d_in[5];
    const float* bq  = (const float*)d_in[6];
    const float* Wk  = (const float*)d_in[7];
    const float* bk  = (const float*)d_in[8];
    const float* Wv  = (const float*)d_in[9];
    const float* bv  = (const float*)d_in[10];
    const float* Wb1 = (const float*)d_in[11];
    const float* bb1 = (const float*)d_in[12];
    const float* Wb2 = (const float*)d_in[13];
    const float* bb2 = (const float*)d_in[14];
    float* out = (float*)d_out;

    // ws layout (73 MiB total)
    char* w = (char*)d_ws;
    u32*   flag  = (u32*)(w);                       // 4 B  (memset to 0)
    unsigned char* canon = (unsigned char*)(w + (1u << 20));   //  8 MiB
    float* qf    = (float*)(w + (16u << 20));       //  8 MiB
    float* kf    = (float*)(w + (24u << 20));       //  8 MiB
    float* vf    = (float*)(w + (32u << 20));       //  8 MiB
    float* h     = (float*)(w + (40u << 20));       // 16 KiB
    float* biasf = (float*)(w + (41u << 20));       // 32 MiB

    hipMemsetAsync(flag, 0, 4, stream);
    mask_detect<<<2048, 256, 0, stream>>>((const u32*)mask, flag);
    mask_canon<<<32768, 256, 0, stream>>>(mask, flag, canon);
    proj_kernel<<<dim3(2048, 3), 256, 0, stream>>>(query, key_, value,
                                                   Wq, Wk, Wv, bq, bk, bv,
                                                   qf, kf, vf);
    mlp1_kernel<<<16, 256, 0, stream>>>(sf, Wb1, bb1, h);
    bias_mlp2<<<1024, 256, 0, stream>>>(h, Wb2, bb2, biasf);
    attn_kernel<<<16384, 256, 0, stream>>>(qf, kf, vf, canon, biasf, out);
}

// Round 6
// 495.850 us; speedup vs baseline: 2.1074x; 2.1074x over previous
//
#include <hip/hip_runtime.h>

// AttentionBiasHead: B=32, L=512, DIM_IN=512, DQ=DK=128, DS=256, DMLP=128
// Round 6: fix round-5 LDS staging width bug (u32x4 = 8 u16, not 16; each
// staging thread must load 4 vectors, not 2). Everything else identical.

typedef unsigned int   u32;
typedef unsigned short u16;
typedef __attribute__((ext_vector_type(8))) short bf16x8;   // 8 bf16 = 4 VGPR
typedef __attribute__((ext_vector_type(4))) float f32x4;
typedef __attribute__((ext_vector_type(4))) u32   u32x4;    // 16B = 8 u16

__device__ __forceinline__ float B2F(u16 x) { return __uint_as_float(((u32)x) << 16); }
__device__ __forceinline__ u16 f2bf(float f) {
    u32 u = __float_as_uint(f);
    return (u16)((u + 0x7fffu + ((u >> 16) & 1u)) >> 16);   // RNE
}

// ---------------------------------------------------------------------------
// Mask dtype detector + canonicalizer (proven r4).
// ---------------------------------------------------------------------------
__global__ __launch_bounds__(256) void mask_detect(const u32* __restrict__ m,
                                                   u32* __restrict__ flag)
{
    const size_t t = (size_t)blockIdx.x * 256 + threadIdx.x;   // grid 2048
    u32 any = 0;
#pragma unroll
    for (int l = 0; l < 4; ++l) any |= (m[t * 4 + l] > 1u) ? 1u : 0u;
    if (__ballot(any)) {
        if ((threadIdx.x & 63) == 0) atomicOr(flag, 1u);
    }
}

__global__ __launch_bounds__(256) void mask_canon(const void* __restrict__ mask,
                                                  const u32* __restrict__ flag,
                                                  unsigned char* __restrict__ canon)
{
    const size_t i = (size_t)blockIdx.x * 256 + threadIdx.x;   // grid 32768
    if (*flag == 0) canon[i] = (((const int*)mask)[i] != 0) ? 1 : 0;
    else            canon[i] = (((const unsigned char*)mask)[i] != 0) ? 1 : 0;
}

// ---------------------------------------------------------------------------
// QKV projection (VALU) -> bf16. q,k row-major; v transposed vT[b][d][l].
// ---------------------------------------------------------------------------
__global__ __launch_bounds__(256) void proj_kernel(
    const float* __restrict__ Xq, const float* __restrict__ Xk, const float* __restrict__ Xv,
    const float* __restrict__ Wq, const float* __restrict__ Wk, const float* __restrict__ Wv,
    const float* __restrict__ Bq, const float* __restrict__ Bk, const float* __restrict__ Bv,
    u16* __restrict__ Yq, u16* __restrict__ Yk, u16* __restrict__ YvT)
{
    const float* X; const float* W; const float* Bi;
    if (blockIdx.y == 0)      { X = Xq; W = Wq; Bi = Bq; }
    else if (blockIdx.y == 1) { X = Xk; W = Wk; Bi = Bk; }
    else                      { X = Xv; W = Wv; Bi = Bv; }

    __shared__ float xs[8 * 512];                 // 16 KiB
    const int tid = threadIdx.x;
    const int R0 = blockIdx.x * 8;                // grid.x = 2048

    const float4* Xf4 = (const float4*)(X + (size_t)R0 * 512);
#pragma unroll
    for (int l = 0; l < 4; ++l)
        *(float4*)&xs[(l * 256 + tid) * 4] = Xf4[l * 256 + tid];
    __syncthreads();

    const int n = tid & 127, rh = tid >> 7;
    float a0 = 0.f, a1 = 0.f, a2 = 0.f, a3 = 0.f;
    for (int d = 0; d < 512; ++d) {
        const float w = W[(size_t)d * 128 + n];
        a0 += xs[(rh * 4 + 0) * 512 + d] * w;
        a1 += xs[(rh * 4 + 1) * 512 + d] * w;
        a2 += xs[(rh * 4 + 2) * 512 + d] * w;
        a3 += xs[(rh * 4 + 3) * 512 + d] * w;
    }
    const float bn = Bi[n];
    if (blockIdx.y < 2) {
        u16* Y = (blockIdx.y == 0) ? Yq : Yk;
        Y[(size_t)(R0 + rh * 4 + 0) * 128 + n] = f2bf(a0 + bn);
        Y[(size_t)(R0 + rh * 4 + 1) * 128 + n] = f2bf(a1 + bn);
        Y[(size_t)(R0 + rh * 4 + 2) * 128 + n] = f2bf(a2 + bn);
        Y[(size_t)(R0 + rh * 4 + 3) * 128 + n] = f2bf(a3 + bn);
    } else {
        const int b = R0 >> 9, l0 = (R0 & 511) + rh * 4;
        u16* T = YvT + (size_t)b * 65536 + (size_t)n * 512;
        T[l0 + 0] = f2bf(a0 + bn);
        T[l0 + 1] = f2bf(a1 + bn);
        T[l0 + 2] = f2bf(a2 + bn);
        T[l0 + 3] = f2bf(a3 + bn);
    }
}

// ---------------------------------------------------------------------------
// h = relu(sf @ Wb1 + bb1)
// ---------------------------------------------------------------------------
__global__ __launch_bounds__(256) void mlp1_kernel(
    const float* __restrict__ sf, const float* __restrict__ Wb1,
    const float* __restrict__ bb1, float* __restrict__ h)
{
    const int t = blockIdx.x * 256 + threadIdx.x;   // grid 16
    const int b = t >> 7, n = t & 127;
    float acc = bb1[n];
    for (int m = 0; m < 256; ++m)
        acc += sf[b * 256 + m] * Wb1[m * 128 + n];
    h[t] = fmaxf(acc, 0.0f);
}

// ---------------------------------------------------------------------------
// bias = h @ Wb2 + bb2 -> bf16. Wb2 (128 MB) streamed once.
// ---------------------------------------------------------------------------
__global__ __launch_bounds__(256) void bias_mlp2(
    const float* __restrict__ h, const float* __restrict__ Wb2,
    const float* __restrict__ bb2, u16* __restrict__ biasb)
{
    __shared__ float hs[4096];
    const int tid = threadIdx.x;
#pragma unroll
    for (int l = 0; l < 16; ++l) hs[l * 256 + tid] = h[l * 256 + tid];
    __syncthreads();

    const size_t n = (size_t)blockIdx.x * 256 + tid;   // grid 1024
    float acc[32];
    const float bb = bb2[n];
#pragma unroll
    for (int b = 0; b < 32; ++b) acc[b] = bb;

    for (int m4 = 0; m4 < 32; ++m4) {
        const float w0 = Wb2[(size_t)(m4 * 4 + 0) * 262144 + n];
        const float w1 = Wb2[(size_t)(m4 * 4 + 1) * 262144 + n];
        const float w2 = Wb2[(size_t)(m4 * 4 + 2) * 262144 + n];
        const float w3 = Wb2[(size_t)(m4 * 4 + 3) * 262144 + n];
#pragma unroll
        for (int b = 0; b < 32; ++b) {
            const float4 hv = *(const float4*)&hs[b * 128 + m4 * 4];
            acc[b] += hv.x * w0 + hv.y * w1 + hv.z * w2 + hv.w * w3;
        }
    }
#pragma unroll
    for (int b = 0; b < 32; ++b)
        biasb[(size_t)b * 262144 + n] = f2bf(acc[b]);
}

// ---------------------------------------------------------------------------
// MFMA attention. Block = 4 waves, 64 q-rows of one batch. grid 256.
// Layouts (HW-verified): A/B elem e of lane l -> [l&15][(l>>4)*8+e];
// C/D reg r of lane l -> [row=(l>>4)*4+r][col=l&15].
// ---------------------------------------------------------------------------
__global__ __launch_bounds__(256, 1) void attn_mfma(
    const u16* __restrict__ qb, const u16* __restrict__ kb, const u16* __restrict__ vTb,
    const unsigned char* __restrict__ canon, const u16* __restrict__ biasb,
    float* __restrict__ out)
{
    __shared__ u16 Qs[64 * 136];    // row stride 136 u16
    __shared__ u16 Ks[64 * 136];
    __shared__ u16 Ps[64 * 72];
    __shared__ u16 Vs[128 * 72];

    const int tid  = threadIdx.x;
    const int w    = tid >> 6;          // wave 0..3
    const int lane = tid & 63;
    const int c    = lane & 15;
    const int qd   = lane >> 4;
    const int bb   = blockIdx.x >> 3;   // batch
    const int it   = blockIdx.x & 7;
    const int i0   = it * 64;

    // ---- stage Q tile [64][128]: 4 thr/row x 32 u16 each ----
    {
        const int r = tid >> 2, sg = tid & 3;
        const u32x4* src = (const u32x4*)(qb + ((size_t)bb * 512 + i0 + r) * 128 + sg * 32);
        u32x4 v0 = src[0], v1 = src[1], v2 = src[2], v3 = src[3];
        u32x4* dst = (u32x4*)&Qs[r * 136 + sg * 32];
        dst[0] = v0; dst[1] = v1; dst[2] = v2; dst[3] = v3;
    }

    // ---- phase 1: scores S[i 16][j 512] per wave, in registers ----
    f32x4 S[8][4];
#pragma unroll
    for (int jt = 0; jt < 8; ++jt)
#pragma unroll
        for (int jj = 0; jj < 4; ++jj) S[jt][jj] = (f32x4){0.f, 0.f, 0.f, 0.f};

    for (int jt = 0; jt < 8; ++jt) {
        __syncthreads();
        {   // stage K tile rows jt*64..+64
            const int r = tid >> 2, sg = tid & 3;
            const u32x4* src = (const u32x4*)(kb + ((size_t)bb * 512 + jt * 64 + r) * 128 + sg * 32);
            u32x4 v0 = src[0], v1 = src[1], v2 = src[2], v3 = src[3];
            u32x4* dst = (u32x4*)&Ks[r * 136 + sg * 32];
            dst[0] = v0; dst[1] = v1; dst[2] = v2; dst[3] = v3;
        }
        __syncthreads();
#pragma unroll
        for (int kc = 0; kc < 4; ++kc) {
            const bf16x8 a = *(const bf16x8*)&Qs[(w * 16 + c) * 136 + kc * 32 + qd * 8];
#pragma unroll
            for (int jj = 0; jj < 4; ++jj) {
                const bf16x8 b = *(const bf16x8*)&Ks[(jj * 16 + c) * 136 + kc * 32 + qd * 8];
                S[jt][jj] = __builtin_amdgcn_mfma_f32_16x16x32_bf16(a, b, S[jt][jj], 0, 0, 0);
            }
        }
    }

    // ---- softmax (registers + 16-lane shuffles) ----
    const float sc = 0.08838834764831845f;   // 1/sqrt(128)
    float inv[4];
#pragma unroll
    for (int r = 0; r < 4; ++r) {
        const unsigned char* mp = canon + ((size_t)bb * 512 + i0 + w * 16 + qd * 4 + r) * 512;
        float mx = -3.4e38f;
#pragma unroll
        for (int jt = 0; jt < 8; ++jt)
#pragma unroll
            for (int jj = 0; jj < 4; ++jj) {
                float s = S[jt][jj][r] * sc;
                if (mp[jt * 64 + jj * 16 + c]) s = 1e-9f;
                S[jt][jj][r] = s;
                mx = fmaxf(mx, s);
            }
#pragma unroll
        for (int o = 1; o < 16; o <<= 1) mx = fmaxf(mx, __shfl_xor(mx, o, 64));
        float sm = 0.f;
#pragma unroll
        for (int jt = 0; jt < 8; ++jt)
#pragma unroll
            for (int jj = 0; jj < 4; ++jj) {
                const float e = __expf(S[jt][jj][r] - mx);
                S[jt][jj][r] = e;
                sm += e;
            }
#pragma unroll
        for (int o = 1; o < 16; o <<= 1) sm += __shfl_xor(sm, o, 64);
        inv[r] = 1.0f / sm;
    }

    // ---- phase 2: out = (softmax + bias) @ v, per-jt P round-trip ----
    f32x4 O[8];
#pragma unroll
    for (int ns = 0; ns < 8; ++ns) O[ns] = (f32x4){0.f, 0.f, 0.f, 0.f};

    for (int jt = 0; jt < 8; ++jt) {
        __syncthreads();
#pragma unroll
        for (int r = 0; r < 4; ++r) {
            const u16* bp = biasb + (size_t)bb * 262144
                          + ((size_t)i0 + w * 16 + qd * 4 + r) * 512 + jt * 64;
#pragma unroll
            for (int jj = 0; jj < 4; ++jj) {
                const float p = S[jt][jj][r] * inv[r] + B2F(bp[jj * 16 + c]);
                Ps[(w * 16 + qd * 4 + r) * 72 + jj * 16 + c] = f2bf(p);
            }
        }
        {   // stage vT subtile [128 d][64 j]: 2 thr/row x 32 u16 each
            const int d = tid >> 1, sg = tid & 1;
            const u32x4* src = (const u32x4*)(vTb + (size_t)bb * 65536 + (size_t)d * 512
                                              + jt * 64 + sg * 32);
            u32x4 v0 = src[0], v1 = src[1], v2 = src[2], v3 = src[3];
            u32x4* dst = (u32x4*)&Vs[d * 72 + sg * 32];
            dst[0] = v0; dst[1] = v1; dst[2] = v2; dst[3] = v3;
        }
        __syncthreads();
#pragma unroll
        for (int kc = 0; kc < 2; ++kc) {
            const bf16x8 a = *(const bf16x8*)&Ps[(w * 16 + c) * 72 + kc * 32 + qd * 8];
#pragma unroll
            for (int ns = 0; ns < 8; ++ns) {
                const bf16x8 b = *(const bf16x8*)&Vs[(ns * 16 + c) * 72 + kc * 32 + qd * 8];
                O[ns] = __builtin_amdgcn_mfma_f32_16x16x32_bf16(a, b, O[ns], 0, 0, 0);
            }
        }
    }

    // ---- write out (f32), C-layout ----
#pragma unroll
    for (int ns = 0; ns < 8; ++ns)
#pragma unroll
        for (int r = 0; r < 4; ++r)
            out[((size_t)bb * 512 + i0 + w * 16 + qd * 4 + r) * 128 + ns * 16 + c] = O[ns][r];
}

// ---------------------------------------------------------------------------
extern "C" void kernel_launch(void* const* d_in, const int* in_sizes, int n_in,
                              void* d_out, int out_size, void* d_ws, size_t ws_size,
                              hipStream_t stream)
{
    const float* query = (const float*)d_in[0];
    const float* key_  = (const float*)d_in[1];
    const float* value = (const float*)d_in[2];
    const float* sf    = (const float*)d_in[3];
    const void*  mask  = d_in[4];
    const float* Wq  = (const float*)d_in[5];
    const float* bq  = (const float*)d_in[6];
    const float* Wk  = (const float*)d_in[7];
    const float* bk  = (const float*)d_in[8];
    const float* Wv  = (const float*)d_in[9];
    const float* bv  = (const float*)d_in[10];
    const float* Wb1 = (const float*)d_in[11];
    const float* bb1 = (const float*)d_in[12];
    const float* Wb2 = (const float*)d_in[13];
    const float* bb2 = (const float*)d_in[14];
    float* out = (float*)d_out;

    // ws layout
    char* w = (char*)d_ws;
    u32*   flag  = (u32*)(w);                                  // 4 B
    unsigned char* canon = (unsigned char*)(w + (1u << 20));   // 8 MiB
    u16*   qb    = (u16*)(w + (16u << 20));                    // 4 MiB
    u16*   kb    = (u16*)(w + (24u << 20));                    // 4 MiB
    u16*   vTb   = (u16*)(w + (32u << 20));                    // 4 MiB
    float* h     = (float*)(w + (40u << 20));                  // 16 KiB
    u16*   biasb = (u16*)(w + (41u << 20));                    // 16 MiB

    hipMemsetAsync(flag, 0, 4, stream);
    mask_detect<<<2048, 256, 0, stream>>>((const u32*)mask, flag);
    mask_canon<<<32768, 256, 0, stream>>>(mask, flag, canon);
    proj_kernel<<<dim3(2048, 3), 256, 0, stream>>>(query, key_, value,
                                                   Wq, Wk, Wv, bq, bk, bv,
                                                   qb, kb, vTb);
    mlp1_kernel<<<16, 256, 0, stream>>>(sf, Wb1, bb1, h);
    bias_mlp2<<<1024, 256, 0, stream>>>(h, Wb2, bb2, biasb);
    attn_mfma<<<256, 256, 0, stream>>>(qb, kb, vTb, canon, biasb, out);
}

// Round 7
// 382.995 us; speedup vs baseline: 2.7284x; 1.2947x over previous
//
#include <hip/hip_runtime.h>

// AttentionBiasHead: B=32, L=512, DIM_IN=512, DQ=DK=128, DS=256, DMLP=128
// Round 7: MFMA projection (wtrans pre-pass + proj_mfma replaces VALU proj).
// v computed with swapped operand roles so C-layout lands transposed (vT).
// attn_mfma / bias_mlp2 / mlp1 / mask kernels unchanged from round 6.

typedef unsigned int   u32;
typedef unsigned short u16;
typedef __attribute__((ext_vector_type(8))) short bf16x8;   // 8 bf16 = 4 VGPR
typedef __attribute__((ext_vector_type(4))) float f32x4;
typedef __attribute__((ext_vector_type(4))) u32   u32x4;    // 16B = 8 u16

__device__ __forceinline__ float B2F(u16 x) { return __uint_as_float(((u32)x) << 16); }
__device__ __forceinline__ u16 f2bf(float f) {
    u32 u = __float_as_uint(f);
    return (u16)((u + 0x7fffu + ((u >> 16) & 1u)) >> 16);   // RNE
}

// ---------------------------------------------------------------------------
// Mask dtype detector + canonicalizer (proven r4).
// ---------------------------------------------------------------------------
__global__ __launch_bounds__(256) void mask_detect(const u32* __restrict__ m,
                                                   u32* __restrict__ flag)
{
    const size_t t = (size_t)blockIdx.x * 256 + threadIdx.x;   // grid 2048
    u32 any = 0;
#pragma unroll
    for (int l = 0; l < 4; ++l) any |= (m[t * 4 + l] > 1u) ? 1u : 0u;
    if (__ballot(any)) {
        if ((threadIdx.x & 63) == 0) atomicOr(flag, 1u);
    }
}

__global__ __launch_bounds__(256) void mask_canon(const void* __restrict__ mask,
                                                  const u32* __restrict__ flag,
                                                  unsigned char* __restrict__ canon)
{
    const size_t i = (size_t)blockIdx.x * 256 + threadIdx.x;   // grid 32768
    if (*flag == 0) canon[i] = (((const int*)mask)[i] != 0) ? 1 : 0;
    else            canon[i] = (((const unsigned char*)mask)[i] != 0) ? 1 : 0;
}

// ---------------------------------------------------------------------------
// W transpose + bf16 convert: WT[s][n=128][k=512] <- W_s[k][n] f32.
// grid (8 k-tiles, 3 streams), 256 thr.
// ---------------------------------------------------------------------------
__global__ __launch_bounds__(256) void wtrans(
    const float* __restrict__ Wq, const float* __restrict__ Wk, const float* __restrict__ Wv,
    u16* __restrict__ WT)
{
    const float* W = (blockIdx.y == 0) ? Wq : (blockIdx.y == 1) ? Wk : Wv;
    __shared__ u16 Ts[64][136];
    const int tid = threadIdx.x, kt = blockIdx.x;

    {   // read [64 k][128 n] coalesced, cvt, store bf16
        const int kk = tid >> 2, nseg = tid & 3;
        const float4* src = (const float4*)(W + (size_t)(kt * 64 + kk) * 128 + nseg * 32);
#pragma unroll
        for (int j = 0; j < 8; ++j) {
            float4 v = src[j];
            Ts[kk][nseg * 32 + j * 4 + 0] = f2bf(v.x);
            Ts[kk][nseg * 32 + j * 4 + 1] = f2bf(v.y);
            Ts[kk][nseg * 32 + j * 4 + 2] = f2bf(v.z);
            Ts[kk][nseg * 32 + j * 4 + 3] = f2bf(v.w);
        }
    }
    __syncthreads();
    {   // write WT[n][k] coalesced
        const int n = tid >> 1, kseg = tid & 1;
        u32 pk[16];
#pragma unroll
        for (int j = 0; j < 16; ++j)
            pk[j] = (u32)Ts[kseg * 32 + 2 * j][n] | ((u32)Ts[kseg * 32 + 2 * j + 1][n] << 16);
        u32x4* dst = (u32x4*)(WT + (size_t)blockIdx.y * 65536 + (size_t)n * 512 + kt * 64 + kseg * 32);
        dst[0] = (u32x4){pk[0], pk[1], pk[2], pk[3]};
        dst[1] = (u32x4){pk[4], pk[5], pk[6], pk[7]};
        dst[2] = (u32x4){pk[8], pk[9], pk[10], pk[11]};
        dst[3] = (u32x4){pk[12], pk[13], pk[14], pk[15]};
    }
}

// ---------------------------------------------------------------------------
// MFMA QKV projection. grid (256 row-tiles, 3 streams), 256 thr (4 waves).
// Tile: 64 rows x 128 cols, BK=64, K=512. X f32 converted to bf16 in staging.
// q/k: A=X(m=row), B=WT(n=col) -> Y[row][n].
// v  : A=WT(m=d),  B=X(n=row)  -> vT[d][row]  (C-layout lands transposed).
// Layouts (HW-verified): A/B elem e of lane l -> [l&15][(l>>4)*8+e];
// C/D reg r of lane l -> [row=(l>>4)*4+r][col=l&15].
// ---------------------------------------------------------------------------
__global__ __launch_bounds__(256) void proj_mfma(
    const float* __restrict__ Xq, const float* __restrict__ Xk, const float* __restrict__ Xv,
    const u16* __restrict__ WT,
    const float* __restrict__ Bq, const float* __restrict__ Bk, const float* __restrict__ Bv,
    u16* __restrict__ Yq, u16* __restrict__ Yk, u16* __restrict__ YvT)
{
    const int s = blockIdx.y;
    const float* X; const float* Bi;
    if (s == 0)      { X = Xq; Bi = Bq; }
    else if (s == 1) { X = Xk; Bi = Bk; }
    else             { X = Xv; Bi = Bv; }
    const u16* Wn = WT + (size_t)s * 65536;    // [n][512] bf16

    __shared__ u16 Xs[64][72];     // rows x K64, stride 144 B (16B-aligned)
    __shared__ u16 Ws[128][72];    // n    x K64

    const int tid  = threadIdx.x;
    const int w    = tid >> 6;
    const int lane = tid & 63;
    const int c    = lane & 15;
    const int qd   = lane >> 4;
    const int R0   = blockIdx.x * 64;

    f32x4 acc[8];
#pragma unroll
    for (int t = 0; t < 8; ++t) acc[t] = (f32x4){0.f, 0.f, 0.f, 0.f};

    for (int kc = 0; kc < 8; ++kc) {
        __syncthreads();
        {   // stage X tile [64][64] f32 -> bf16
            const int row = tid >> 2, seg = tid & 3;
            const float4* src = (const float4*)(X + (size_t)(R0 + row) * 512 + kc * 64 + seg * 16);
            float4 v0 = src[0], v1 = src[1], v2 = src[2], v3 = src[3];
            u32 pk[8];
            pk[0] = (u32)f2bf(v0.x) | ((u32)f2bf(v0.y) << 16);
            pk[1] = (u32)f2bf(v0.z) | ((u32)f2bf(v0.w) << 16);
            pk[2] = (u32)f2bf(v1.x) | ((u32)f2bf(v1.y) << 16);
            pk[3] = (u32)f2bf(v1.z) | ((u32)f2bf(v1.w) << 16);
            pk[4] = (u32)f2bf(v2.x) | ((u32)f2bf(v2.y) << 16);
            pk[5] = (u32)f2bf(v2.z) | ((u32)f2bf(v2.w) << 16);
            pk[6] = (u32)f2bf(v3.x) | ((u32)f2bf(v3.y) << 16);
            pk[7] = (u32)f2bf(v3.z) | ((u32)f2bf(v3.w) << 16);
            u32x4* dst = (u32x4*)&Xs[row][seg * 16];
            dst[0] = (u32x4){pk[0], pk[1], pk[2], pk[3]};
            dst[1] = (u32x4){pk[4], pk[5], pk[6], pk[7]};
        }
        {   // stage W tile [128 n][64 k] bf16 (already converted)
            const int n = tid >> 1, seg = tid & 1;
            const u32x4* src = (const u32x4*)(Wn + (size_t)n * 512 + kc * 64 + seg * 32);
            u32x4 v0 = src[0], v1 = src[1], v2 = src[2], v3 = src[3];
            u32x4* dst = (u32x4*)&Ws[n][seg * 32];
            dst[0] = v0; dst[1] = v1; dst[2] = v2; dst[3] = v3;
        }
        __syncthreads();

#pragma unroll
        for (int ks = 0; ks < 2; ++ks) {
            if (s < 2) {
                const bf16x8 a = *(const bf16x8*)&Xs[w * 16 + c][ks * 32 + qd * 8];
#pragma unroll
                for (int nt = 0; nt < 8; ++nt) {
                    const bf16x8 b = *(const bf16x8*)&Ws[nt * 16 + c][ks * 32 + qd * 8];
                    acc[nt] = __builtin_amdgcn_mfma_f32_16x16x32_bf16(a, b, acc[nt], 0, 0, 0);
                }
            } else {
#pragma unroll
                for (int t = 0; t < 2; ++t) {
                    const bf16x8 a = *(const bf16x8*)&Ws[(2 * w + t) * 16 + c][ks * 32 + qd * 8];
#pragma unroll
                    for (int it = 0; it < 4; ++it) {
                        const bf16x8 b = *(const bf16x8*)&Xs[it * 16 + c][ks * 32 + qd * 8];
                        acc[t * 4 + it] = __builtin_amdgcn_mfma_f32_16x16x32_bf16(a, b, acc[t * 4 + it], 0, 0, 0);
                    }
                }
            }
        }
    }

    if (s < 2) {
        u16* Y = (s == 0) ? Yq : Yk;
#pragma unroll
        for (int nt = 0; nt < 8; ++nt) {
            const float bn = Bi[nt * 16 + c];
#pragma unroll
            for (int r = 0; r < 4; ++r)
                Y[(size_t)(R0 + w * 16 + qd * 4 + r) * 128 + nt * 16 + c] = f2bf(acc[nt][r] + bn);
        }
    } else {
        const int bb = blockIdx.x >> 3, il0 = R0 & 511;
#pragma unroll
        for (int t = 0; t < 2; ++t)
#pragma unroll
            for (int r = 0; r < 4; ++r) {
                const int d = (2 * w + t) * 16 + qd * 4 + r;
                const float bd = Bi[d];
#pragma unroll
                for (int it = 0; it < 4; ++it)
                    YvT[(size_t)bb * 65536 + (size_t)d * 512 + il0 + it * 16 + c] =
                        f2bf(acc[t * 4 + it][r] + bd);
            }
    }
}

// ---------------------------------------------------------------------------
// h = relu(sf @ Wb1 + bb1)
// ---------------------------------------------------------------------------
__global__ __launch_bounds__(256) void mlp1_kernel(
    const float* __restrict__ sf, const float* __restrict__ Wb1,
    const float* __restrict__ bb1, float* __restrict__ h)
{
    const int t = blockIdx.x * 256 + threadIdx.x;   // grid 16
    const int b = t >> 7, n = t & 127;
    float acc = bb1[n];
    for (int m = 0; m < 256; ++m)
        acc += sf[b * 256 + m] * Wb1[m * 128 + n];
    h[t] = fmaxf(acc, 0.0f);
}

// ---------------------------------------------------------------------------
// bias = h @ Wb2 + bb2 -> bf16. Wb2 (128 MB) streamed once.
// ---------------------------------------------------------------------------
__global__ __launch_bounds__(256) void bias_mlp2(
    const float* __restrict__ h, const float* __restrict__ Wb2,
    const float* __restrict__ bb2, u16* __restrict__ biasb)
{
    __shared__ float hs[4096];
    const int tid = threadIdx.x;
#pragma unroll
    for (int l = 0; l < 16; ++l) hs[l * 256 + tid] = h[l * 256 + tid];
    __syncthreads();

    const size_t n = (size_t)blockIdx.x * 256 + tid;   // grid 1024
    float acc[32];
    const float bb = bb2[n];
#pragma unroll
    for (int b = 0; b < 32; ++b) acc[b] = bb;

    for (int m4 = 0; m4 < 32; ++m4) {
        const float w0 = Wb2[(size_t)(m4 * 4 + 0) * 262144 + n];
        const float w1 = Wb2[(size_t)(m4 * 4 + 1) * 262144 + n];
        const float w2 = Wb2[(size_t)(m4 * 4 + 2) * 262144 + n];
        const float w3 = Wb2[(size_t)(m4 * 4 + 3) * 262144 + n];
#pragma unroll
        for (int b = 0; b < 32; ++b) {
            const float4 hv = *(const float4*)&hs[b * 128 + m4 * 4];
            acc[b] += hv.x * w0 + hv.y * w1 + hv.z * w2 + hv.w * w3;
        }
    }
#pragma unroll
    for (int b = 0; b < 32; ++b)
        biasb[(size_t)b * 262144 + n] = f2bf(acc[b]);
}

// ---------------------------------------------------------------------------
// MFMA attention (proven r6). Block = 4 waves, 64 q-rows. grid 256.
// ---------------------------------------------------------------------------
__global__ __launch_bounds__(256, 1) void attn_mfma(
    const u16* __restrict__ qb, const u16* __restrict__ kb, const u16* __restrict__ vTb,
    const unsigned char* __restrict__ canon, const u16* __restrict__ biasb,
    float* __restrict__ out)
{
    __shared__ u16 Qs[64 * 136];
    __shared__ u16 Ks[64 * 136];
    __shared__ u16 Ps[64 * 72];
    __shared__ u16 Vs[128 * 72];

    const int tid  = threadIdx.x;
    const int w    = tid >> 6;
    const int lane = tid & 63;
    const int c    = lane & 15;
    const int qd   = lane >> 4;
    const int bb   = blockIdx.x >> 3;
    const int it   = blockIdx.x & 7;
    const int i0   = it * 64;

    {
        const int r = tid >> 2, sg = tid & 3;
        const u32x4* src = (const u32x4*)(qb + ((size_t)bb * 512 + i0 + r) * 128 + sg * 32);
        u32x4 v0 = src[0], v1 = src[1], v2 = src[2], v3 = src[3];
        u32x4* dst = (u32x4*)&Qs[r * 136 + sg * 32];
        dst[0] = v0; dst[1] = v1; dst[2] = v2; dst[3] = v3;
    }

    f32x4 S[8][4];
#pragma unroll
    for (int jt = 0; jt < 8; ++jt)
#pragma unroll
        for (int jj = 0; jj < 4; ++jj) S[jt][jj] = (f32x4){0.f, 0.f, 0.f, 0.f};

    for (int jt = 0; jt < 8; ++jt) {
        __syncthreads();
        {
            const int r = tid >> 2, sg = tid & 3;
            const u32x4* src = (const u32x4*)(kb + ((size_t)bb * 512 + jt * 64 + r) * 128 + sg * 32);
            u32x4 v0 = src[0], v1 = src[1], v2 = src[2], v3 = src[3];
            u32x4* dst = (u32x4*)&Ks[r * 136 + sg * 32];
            dst[0] = v0; dst[1] = v1; dst[2] = v2; dst[3] = v3;
        }
        __syncthreads();
#pragma unroll
        for (int kc = 0; kc < 4; ++kc) {
            const bf16x8 a = *(const bf16x8*)&Qs[(w * 16 + c) * 136 + kc * 32 + qd * 8];
#pragma unroll
            for (int jj = 0; jj < 4; ++jj) {
                const bf16x8 b = *(const bf16x8*)&Ks[(jj * 16 + c) * 136 + kc * 32 + qd * 8];
                S[jt][jj] = __builtin_amdgcn_mfma_f32_16x16x32_bf16(a, b, S[jt][jj], 0, 0, 0);
            }
        }
    }

    const float sc = 0.08838834764831845f;
    float inv[4];
#pragma unroll
    for (int r = 0; r < 4; ++r) {
        const unsigned char* mp = canon + ((size_t)bb * 512 + i0 + w * 16 + qd * 4 + r) * 512;
        float mx = -3.4e38f;
#pragma unroll
        for (int jt = 0; jt < 8; ++jt)
#pragma unroll
            for (int jj = 0; jj < 4; ++jj) {
                float s = S[jt][jj][r] * sc;
                if (mp[jt * 64 + jj * 16 + c]) s = 1e-9f;
                S[jt][jj][r] = s;
                mx = fmaxf(mx, s);
            }
#pragma unroll
        for (int o = 1; o < 16; o <<= 1) mx = fmaxf(mx, __shfl_xor(mx, o, 64));
        float sm = 0.f;
#pragma unroll
        for (int jt = 0; jt < 8; ++jt)
#pragma unroll
            for (int jj = 0; jj < 4; ++jj) {
                const float e = __expf(S[jt][jj][r] - mx);
                S[jt][jj][r] = e;
                sm += e;
            }
#pragma unroll
        for (int o = 1; o < 16; o <<= 1) sm += __shfl_xor(sm, o, 64);
        inv[r] = 1.0f / sm;
    }

    f32x4 O[8];
#pragma unroll
    for (int ns = 0; ns < 8; ++ns) O[ns] = (f32x4){0.f, 0.f, 0.f, 0.f};

    for (int jt = 0; jt < 8; ++jt) {
        __syncthreads();
#pragma unroll
        for (int r = 0; r < 4; ++r) {
            const u16* bp = biasb + (size_t)bb * 262144
                          + ((size_t)i0 + w * 16 + qd * 4 + r) * 512 + jt * 64;
#pragma unroll
            for (int jj = 0; jj < 4; ++jj) {
                const float p = S[jt][jj][r] * inv[r] + B2F(bp[jj * 16 + c]);
                Ps[(w * 16 + qd * 4 + r) * 72 + jj * 16 + c] = f2bf(p);
            }
        }
        {
            const int d = tid >> 1, sg = tid & 1;
            const u32x4* src = (const u32x4*)(vTb + (size_t)bb * 65536 + (size_t)d * 512
                                              + jt * 64 + sg * 32);
            u32x4 v0 = src[0], v1 = src[1], v2 = src[2], v3 = src[3];
            u32x4* dst = (u32x4*)&Vs[d * 72 + sg * 32];
            dst[0] = v0; dst[1] = v1; dst[2] = v2; dst[3] = v3;
        }
        __syncthreads();
#pragma unroll
        for (int kc = 0; kc < 2; ++kc) {
            const bf16x8 a = *(const bf16x8*)&Ps[(w * 16 + c) * 72 + kc * 32 + qd * 8];
#pragma unroll
            for (int ns = 0; ns < 8; ++ns) {
                const bf16x8 b = *(const bf16x8*)&Vs[(ns * 16 + c) * 72 + kc * 32 + qd * 8];
                O[ns] = __builtin_amdgcn_mfma_f32_16x16x32_bf16(a, b, O[ns], 0, 0, 0);
            }
        }
    }

#pragma unroll
    for (int ns = 0; ns < 8; ++ns)
#pragma unroll
        for (int r = 0; r < 4; ++r)
            out[((size_t)bb * 512 + i0 + w * 16 + qd * 4 + r) * 128 + ns * 16 + c] = O[ns][r];
}

// ---------------------------------------------------------------------------
extern "C" void kernel_launch(void* const* d_in, const int* in_sizes, int n_in,
                              void* d_out, int out_size, void* d_ws, size_t ws_size,
                              hipStream_t stream)
{
    const float* query = (const float*)d_in[0];
    const float* key_  = (const float*)d_in[1];
    const float* value = (const float*)d_in[2];
    const float* sf    = (const float*)d_in[3];
    const void*  mask  = d_in[4];
    const float* Wq  = (const float*)d_in[5];
    const float* bq  = (const float*)d_in[6];
    const float* Wk  = (const float*)d_in[7];
    const float* bk  = (const float*)d_in[8];
    const float* Wv  = (const float*)d_in[9];
    const float* bv  = (const float*)d_in[10];
    const float* Wb1 = (const float*)d_in[11];
    const float* bb1 = (const float*)d_in[12];
    const float* Wb2 = (const float*)d_in[13];
    const float* bb2 = (const float*)d_in[14];
    float* out = (float*)d_out;

    // ws layout
    char* w = (char*)d_ws;
    u32*   flag  = (u32*)(w);                                  // 4 B
    unsigned char* canon = (unsigned char*)(w + (1u << 20));   // 8 MiB
    u16*   qb    = (u16*)(w + (16u << 20));                    // 4 MiB
    u16*   kb    = (u16*)(w + (24u << 20));                    // 4 MiB
    u16*   vTb   = (u16*)(w + (32u << 20));                    // 4 MiB
    float* h     = (float*)(w + (40u << 20));                  // 16 KiB
    u16*   biasb = (u16*)(w + (41u << 20));                    // 16 MiB
    u16*   WT    = (u16*)(w + (58u << 20));                    // 384 KiB

    hipMemsetAsync(flag, 0, 4, stream);
    mask_detect<<<2048, 256, 0, stream>>>((const u32*)mask, flag);
    mask_canon<<<32768, 256, 0, stream>>>(mask, flag, canon);
    wtrans<<<dim3(8, 3), 256, 0, stream>>>(Wq, Wk, Wv, WT);
    proj_mfma<<<dim3(256, 3), 256, 0, stream>>>(query, key_, value, WT,
                                                bq, bk, bv, qb, kb, vTb);
    mlp1_kernel<<<16, 256, 0, stream>>>(sf, Wb1, bb1, h);
    bias_mlp2<<<1024, 256, 0, stream>>>(h, Wb2, bb2, biasb);
    attn_mfma<<<256, 256, 0, stream>>>(qb, kb, vTb, canon, biasb, out);
}